// Round 5
// baseline (114.304 us; speedup 1.0000x reference)
//
#include <hip/hip_runtime.h>
#include <hip/hip_bf16.h>

#define TWO_N  8192
#define N_HALF 4096
#define DIMS   256

typedef __bf16 bf16x8 __attribute__((ext_vector_type(8)));
typedef float  f32x4  __attribute__((ext_vector_type(4)));
typedef unsigned short ushort8v __attribute__((ext_vector_type(8)));

__device__ __forceinline__ float fast_exp2(float x) {
#if __has_builtin(__builtin_amdgcn_exp2f)
    return __builtin_amdgcn_exp2f(x);
#else
    float r; asm("v_exp_f32 %0, %1" : "=v"(r) : "v"(x)); return r;
#endif
}

// ---------------------------------------------------------------------------
// Kernel 1: normalize rows of reps = cat([zjs, zis]), pre-scale by
// sqrt(2*log2(e)) so the MFMA dot equals (1/TEMP)*log2(e)*sim, store in MFMA
// fragment-swizzled order: chunk = ((row/16)*8 + kk)*64 + quad*16 + (row%16);
// chunk = 8 bf16 = elements k in [quad*8 + kk*32, +8) of that row.
// ---------------------------------------------------------------------------
__global__ __launch_bounds__(256) void nrm_kernel(const float* __restrict__ zis,
                                                  const float* __restrict__ zjs,
                                                  unsigned short* __restrict__ swz)
{
    const int tid = threadIdx.x;
    const int l32 = tid & 31;
    const int row = blockIdx.x * 8 + (tid >> 5);
    const int k0  = l32 * 8;

    const float* src = (row < N_HALF) ? (zjs + (size_t)row * DIMS)
                                      : (zis + (size_t)(row - N_HALF) * DIMS);
    const float4 v0 = reinterpret_cast<const float4*>(src + k0)[0];
    const float4 v1 = reinterpret_cast<const float4*>(src + k0 + 4)[0];
    float ss = v0.x * v0.x + v0.y * v0.y + v0.z * v0.z + v0.w * v0.w
             + v1.x * v1.x + v1.y * v1.y + v1.z * v1.z + v1.w * v1.w;
#pragma unroll
    for (int m = 1; m < 32; m <<= 1) ss += __shfl_xor(ss, m, 64);
    // norms ~16 for N(0,1) rows; cosine eps path can never trigger
    const float inv = rsqrtf(ss) * 1.69864360045f;  // * sqrt(2*log2(e))

    const float vals[8] = {v0.x, v0.y, v0.z, v0.w, v1.x, v1.y, v1.z, v1.w};
    ushort8v o;
#pragma unroll
    for (int j = 0; j < 8; ++j) {
        __hip_bfloat16 b = __float2bfloat16(vals[j] * inv);
        o[j] = *reinterpret_cast<unsigned short*>(&b);
    }
    const int chunk = ((row >> 4) * 8 + (l32 >> 2)) * 64 + (l32 & 3) * 16 + (row & 15);
    *reinterpret_cast<ushort8v*>(swz + (size_t)chunk * 8) = o;
}

// ---------------------------------------------------------------------------
// Kernel 2: fused scaled-Gram (bf16 MFMA) + exp2 partial row sums + diag mask
// + positive extraction.
//
// Grid 2048 x 256 (4 waves). Block tile: 256 rows x 128 cols.
//   xcd = bid&7, j = bid>>3:  strip = xcd*8 + (j&7)  (64 strips of 128 cols;
//   all 32 blocks sharing a strip land on one XCD's L2), rowgrp = j>>3.
// The ENTIRE 64 KB A strip (128 cols x K=256, contiguous in the swizzled
// buffer) is staged into LDS ONCE via global_load_lds(16B), one barrier,
// then 8 tile iterations run on LDS+registers only — no barriers, no global
// loads in the hot loop (A register-double-buffered from LDS).
// Wave w owns rows [rowgrp*256 + w*64, +64): B frags = 128 VGPR, 4 MFMA chains.
// ---------------------------------------------------------------------------
__global__ __launch_bounds__(256, 2) void ntx_kernel(const __bf16* __restrict__ swz,
                                                     float* __restrict__ rowsum_part,
                                                     float* __restrict__ pos_part)
{
    __shared__ __align__(16) unsigned char atile[65536];

    const int tid  = threadIdx.x;
    const int lane = tid & 63;
    const int wave = tid >> 6;
    const int l15  = lane & 15;
    const int quad = lane >> 4;

    const int xcd    = blockIdx.x & 7;
    const int j      = blockIdx.x >> 3;
    const int strip  = xcd * 8 + (j & 7);
    const int rowgrp = j >> 3;
    const int wr0    = rowgrp * 256 + wave * 64;
    const int c_base = strip * 128;
    const int p0     = wr0 ^ N_HALF;     // partner (positive) col block

    // ---- Stage the full 64 KB A strip into LDS (cols c_base..c_base+127).
    {
        const unsigned char* gsrc =
            (const unsigned char*)swz + (size_t)strip * 65536 + wave * 1024 + (lane & 63) * 16;
        auto* ldst = (__attribute__((address_space(3))) unsigned char*)atile + wave * 1024;
#pragma unroll
        for (int i = 0; i < 16; ++i)
            __builtin_amdgcn_global_load_lds(
                (const __attribute__((address_space(1))) unsigned char*)(gsrc + i * 4096),
                ldst + i * 4096, 16, 0, 0);
    }

    // ---- Hoist B (row) fragments while the stage is in flight.
    bf16x8 bfrag[4][8];
#pragma unroll
    for (int t = 0; t < 4; ++t) {
        const __bf16* bp = swz + (size_t)((wr0 >> 4) + t) * 4096 + lane * 8;
#pragma unroll
        for (int kk = 0; kk < 8; ++kk)
            bfrag[t][kk] = *reinterpret_cast<const bf16x8*>(bp + kk * 512);
    }

    __syncthreads();   // single barrier: stage complete (vmcnt drained here)

    float sum_exp[4] = {0.f, 0.f, 0.f, 0.f};
    float pos_acc = 0.f;

    const __bf16* lp = (const __bf16*)atile + lane * 8;

    auto load_tile = [&](bf16x8* a, int it) {
#pragma unroll
        for (int kk = 0; kk < 8; ++kk)
            a[kk] = *reinterpret_cast<const bf16x8*>(lp + it * 4096 + kk * 512);
    };

    auto compute = [&](const bf16x8* a, int it) {
        f32x4 acc[4] = {{0.f, 0.f, 0.f, 0.f}, {0.f, 0.f, 0.f, 0.f},
                        {0.f, 0.f, 0.f, 0.f}, {0.f, 0.f, 0.f, 0.f}};
#pragma unroll
        for (int kk = 0; kk < 8; ++kk) {
#pragma unroll
            for (int t = 0; t < 4; ++t)
                acc[t] = __builtin_amdgcn_mfma_f32_16x16x32_bf16(
                    a[kk], bfrag[t][kk], acc[t], 0, 0, 0);
        }
        // acc = (1/TEMP)*log2(e)*sim ; D: row = wr0+t*16+l15, col = c0+quad*4+j
        const int c0 = c_base + it * 16;
        const bool special = (c0 < wr0 + 64 && c0 + 16 > wr0) ||
                             (c0 < p0 + 64 && c0 + 16 > p0);
        if (!special) {
#pragma unroll
            for (int t = 0; t < 4; ++t) {
                float e0 = fast_exp2(acc[t][0]) + fast_exp2(acc[t][1]);
                float e1 = fast_exp2(acc[t][2]) + fast_exp2(acc[t][3]);
                sum_exp[t] += e0 + e1;
            }
        } else {
#pragma unroll
            for (int t = 0; t < 4; ++t) {
                const int r = wr0 + t * 16 + l15;
#pragma unroll
                for (int jj = 0; jj < 4; ++jj) {
                    const int c = c0 + quad * 4 + jj;
                    const float e = fast_exp2(acc[t][jj]);
                    sum_exp[t] += (c == r) ? 0.f : e;               // self-diag mask
                    if (c == (r ^ N_HALF)) pos_acc += acc[t][jj];   // positive (scaled)
                }
            }
        }
    };

    // 8 tiles, register double-buffered from LDS, barrier-free.
    bf16x8 a0[8], a1[8];
    load_tile(a0, 0);
#pragma unroll 1
    for (int it = 0; it < 8; it += 2) {
        load_tile(a1, it + 1);
        compute(a0, it);
        if (it + 2 < 8) load_tile(a0, it + 2);
        compute(a1, it + 1);
    }

    // Per-row partial: reduce over the 4 quads, one coalesced store per row.
#pragma unroll
    for (int t = 0; t < 4; ++t) {
        float s = sum_exp[t];
        s += __shfl_xor(s, 16, 64);
        s += __shfl_xor(s, 32, 64);
        if (lane < 16)
            rowsum_part[(size_t)strip * TWO_N + wr0 + t * 16 + lane] = s;
    }

    // Positive partial: every wave writes its slot (0 if no partner overlap).
#pragma unroll
    for (int m = 1; m < 64; m <<= 1) pos_acc += __shfl_xor(pos_acc, m, 64);
    if (lane == 0) pos_part[blockIdx.x * 4 + wave] = pos_acc;
}

// ---------------------------------------------------------------------------
// Kernel 3: per-row ln(sum of 64 partials) - ln2 * positive partials, reduced.
// 8 blocks x 1024 threads; every thread also folds one pos slot (8192 total).
// ---------------------------------------------------------------------------
__global__ __launch_bounds__(1024) void fin1_kernel(const float* __restrict__ rowsum_part,
                                                    const float* __restrict__ pos_part,
                                                    float* __restrict__ block_part)
{
    __shared__ float red[16];
    const int t = threadIdx.x;
    const int r = blockIdx.x * 1024 + t;
    float acc = 0.f;
#pragma unroll
    for (int cs = 0; cs < 64; ++cs)
        acc += rowsum_part[(size_t)cs * TWO_N + r];
    float v = logf(acc) - 0.69314718055994531f * pos_part[blockIdx.x * 1024 + t];
#pragma unroll
    for (int m = 1; m < 64; m <<= 1) v += __shfl_xor(v, m, 64);
    if ((t & 63) == 0) red[t >> 6] = v;
    __syncthreads();
    if (t == 0) {
        float s = 0.f;
#pragma unroll
        for (int w = 0; w < 16; ++w) s += red[w];
        block_part[blockIdx.x] = s;
    }
}

__global__ void fin2_kernel(const float* __restrict__ block_part, float* __restrict__ out)
{
    if (threadIdx.x == 0) {
        float s = 0.f;
#pragma unroll
        for (int i = 0; i < 8; ++i) s += block_part[i];
        out[0] = s / (float)TWO_N;
    }
}

// ---------------------------------------------------------------------------
extern "C" void kernel_launch(void* const* d_in, const int* in_sizes, int n_in,
                              void* d_out, int out_size, void* d_ws, size_t ws_size,
                              hipStream_t stream)
{
    const float* zis = (const float*)d_in[0];
    const float* zjs = (const float*)d_in[1];

    // ws: [0,4MB) swizzled bf16; rowsum partials [64][8192] (2MB);
    //     pos partials [8192]; block partials [8].
    unsigned short* swz = (unsigned short*)d_ws;
    float* rowsum_part  = (float*)((char*)d_ws + (size_t)TWO_N * DIMS * sizeof(unsigned short));
    float* pos_part     = rowsum_part + (size_t)64 * TWO_N;
    float* block_part   = pos_part + 8192;

    nrm_kernel<<<TWO_N / 8, 256, 0, stream>>>(zis, zjs, swz);
    ntx_kernel<<<2048, 256, 0, stream>>>((const __bf16*)swz, rowsum_part, pos_part);
    fin1_kernel<<<8, 1024, 0, stream>>>(rowsum_part, pos_part, block_part);
    fin2_kernel<<<1, 64, 0, stream>>>(block_part, (float*)d_out);
}

// Round 7
// 98.436 us; speedup vs baseline: 1.1612x; 1.1612x over previous
//
#include <hip/hip_runtime.h>
#include <hip/hip_bf16.h>

#define TWO_N  8192
#define N_HALF 4096
#define DIMS   256

typedef float f32x4 __attribute__((ext_vector_type(4)));
typedef int   int4v __attribute__((ext_vector_type(4)));
typedef int   int8v __attribute__((ext_vector_type(8)));

#define SCALE_NEUTRAL 0x7F7F7F7F   // E8M0 127 = 2^0 in all 4 bytes

__device__ __forceinline__ float fast_exp2(float x) {
#if defined(__HIP_DEVICE_COMPILE__) && __has_builtin(__builtin_amdgcn_exp2f)
    return __builtin_amdgcn_exp2f(x);
#else
    float r; asm("v_exp_f32 %0, %1" : "=v"(r) : "v"(x)); return r;
#endif
}

// Build a 32-byte MFMA fragment from two 16-byte halves 1024 B apart.
// Both A (LDS) and B (global) operands use this same byte order, so the
// ISA's internal K-ordering cancels in the dot product.
template <typename P>
__device__ __forceinline__ int8v frag32(const P* p) {
    int4v lo = *reinterpret_cast<const int4v*>(p);
    int4v hi = *reinterpret_cast<const int4v*>((const unsigned char*)p + 1024);
    int8v r;
    r[0] = lo[0]; r[1] = lo[1]; r[2] = lo[2]; r[3] = lo[3];
    r[4] = hi[0]; r[5] = hi[1]; r[6] = hi[2]; r[7] = hi[3];
    return r;
}

// ---------------------------------------------------------------------------
// Kernel 1: normalize rows of reps = cat([zjs, zis]), pre-scale by
// sqrt(2*log2(e)) (so the fp8 dot = (1/TEMP)*log2(e)*sim), quantize to
// OCP fp8 e4m3, and store fragment-swizzled:
//   chunk(g = row/16, kc = k/128) at (g*2+kc)*2048; within chunk, logical
//   k' = k%128 maps to byte (k'>>4 ? ...) via: q = k'>>5, b = k'&31,
//   h = b>>4 -> byte h*1024 + ((row&15) + 16*q)*16 + (b&15).
// 32 threads per row, 8 k's each -> one aligned 8-byte store per thread.
// ---------------------------------------------------------------------------
__global__ __launch_bounds__(256) void nrm_kernel(const float* __restrict__ zis,
                                                  const float* __restrict__ zjs,
                                                  unsigned char* __restrict__ swz)
{
    const int tid = threadIdx.x;
    const int l32 = tid & 31;
    const int row = blockIdx.x * 8 + (tid >> 5);
    const int k0  = l32 * 8;

    const float* src = (row < N_HALF) ? (zjs + (size_t)row * DIMS)
                                      : (zis + (size_t)(row - N_HALF) * DIMS);
    const float4 v0 = reinterpret_cast<const float4*>(src + k0)[0];
    const float4 v1 = reinterpret_cast<const float4*>(src + k0 + 4)[0];
    float ss = v0.x * v0.x + v0.y * v0.y + v0.z * v0.z + v0.w * v0.w
             + v1.x * v1.x + v1.y * v1.y + v1.z * v1.z + v1.w * v1.w;
#pragma unroll
    for (int m = 1; m < 32; m <<= 1) ss += __shfl_xor(ss, m, 64);
    // norms ~16 for N(0,1) rows; cosine eps path can never trigger
    const float inv = rsqrtf(ss) * 1.69864360045f;  // * sqrt(2*log2(e))

    const float a0 = v0.x * inv, a1 = v0.y * inv, a2 = v0.z * inv, a3 = v0.w * inv;
    const float a4 = v1.x * inv, a5 = v1.y * inv, a6 = v1.z * inv, a7 = v1.w * inv;

    int lo, hi;
#if defined(__HIP_DEVICE_COMPILE__)
    lo = __builtin_amdgcn_cvt_pk_fp8_f32(a0, a1, 0, false);
    lo = __builtin_amdgcn_cvt_pk_fp8_f32(a2, a3, lo, true);
    hi = __builtin_amdgcn_cvt_pk_fp8_f32(a4, a5, 0, false);
    hi = __builtin_amdgcn_cvt_pk_fp8_f32(a6, a7, hi, true);
#else
    lo = hi = 0;   // host pass never executes this body
#endif

    const int g  = row >> 4;
    const int kc = (l32 >> 4) & 1;
    const int q  = (l32 >> 2) & 3;
    const int h  = (l32 >> 1) & 1;
    const int j8 = (l32 & 1) * 8;
    const int m  = row & 15;
    const size_t off = (size_t)(g * 2 + kc) * 2048 + h * 1024 + (m + 16 * q) * 16 + j8;
    int2 o; o.x = lo; o.y = hi;
    *reinterpret_cast<int2*>(swz + off) = o;
}

// ---------------------------------------------------------------------------
// Kernel 2: fused scaled-Gram (MX-fp8 MFMA, neutral scales) + exp2 partial
// row sums + diag mask + positive extraction.
//
// Grid 2048 x 256 (4 waves). Block tile: 256 rows x 128 cols.
//   strip = (bid&7)*8 + ((bid>>3)&7)  (64 col-strips; 32 blocks sharing a
//   strip land on one XCD), rowgrp = bid>>6.
// The 32 KB fp8 A strip (128 cols x K=256) is staged once into LDS
// (global_load_lds x8/thread), one barrier; B frags (4 row-groups x 2
// K-chunks = 64 VGPR) hoisted from L2. Hot loop: 8 col-tiles FULLY UNROLLED
// (defeats the B-fragment rematerialization seen in R2-R5: VGPR=92 < the
// declared hoist), each tile = 4 ds_read_b128 + 8 mfma_scale + 16 exp2.
// ---------------------------------------------------------------------------
__global__ __launch_bounds__(256, 3) void ntx_kernel(const unsigned char* __restrict__ swz,
                                                     float* __restrict__ rowsum_part,
                                                     float* __restrict__ pos_part)
{
    __shared__ __align__(16) unsigned char atile[32768];

    const int tid  = threadIdx.x;
    const int lane = tid & 63;
    const int wave = tid >> 6;
    const int l15  = lane & 15;
    const int quad = lane >> 4;

    const int strip  = (blockIdx.x & 7) * 8 + ((blockIdx.x >> 3) & 7);
    const int rowgrp = blockIdx.x >> 6;
    const int wr0    = rowgrp * 256 + wave * 64;
    const int c_base = strip * 128;
    const int p0     = wr0 ^ N_HALF;     // partner (positive) col block

    // ---- Stage the 32 KB fp8 A strip into LDS (verbatim copy).
    {
        const unsigned char* gsrc = swz + (size_t)strip * 32768 + tid * 16;
        auto* ldst = (__attribute__((address_space(3))) unsigned char*)atile + tid * 16;
#pragma unroll
        for (int i = 0; i < 8; ++i)
            __builtin_amdgcn_global_load_lds(
                (const __attribute__((address_space(1))) unsigned char*)(gsrc + i * 4096),
                ldst + i * 4096, 16, 0, 0);
    }

    // ---- Hoist B (row) fragments: 4 groups of 16 rows x 2 K-chunks = 64 VGPR.
    int8v bfrag[4][2];
#pragma unroll
    for (int t = 0; t < 4; ++t) {
        const int gr = (wr0 >> 4) + t;
#pragma unroll
        for (int kc = 0; kc < 2; ++kc)
            bfrag[t][kc] = frag32(swz + (size_t)(gr * 2 + kc) * 2048 + lane * 16);
    }

    __syncthreads();   // stage complete (also drains the B-hoist vmcnt)

    float sum_exp[4] = {0.f, 0.f, 0.f, 0.f};
    float pos_acc = 0.f;

#pragma unroll
    for (int cg = 0; cg < 8; ++cg) {
        int8v a[2];
#pragma unroll
        for (int kc = 0; kc < 2; ++kc)
            a[kc] = frag32(atile + (cg * 2 + kc) * 2048 + lane * 16);

        f32x4 acc[4] = {{0.f, 0.f, 0.f, 0.f}, {0.f, 0.f, 0.f, 0.f},
                        {0.f, 0.f, 0.f, 0.f}, {0.f, 0.f, 0.f, 0.f}};
#pragma unroll
        for (int kc = 0; kc < 2; ++kc) {
#pragma unroll
            for (int t = 0; t < 4; ++t)
                acc[t] = __builtin_amdgcn_mfma_scale_f32_16x16x128_f8f6f4(
                    a[kc], bfrag[t][kc], acc[t], 0, 0,
                    0, SCALE_NEUTRAL, 0, SCALE_NEUTRAL);
        }

        // acc = (1/TEMP)*log2(e)*sim ; D: row = wr0+t*16+l15, col = c0+quad*4+j
        const int c0 = c_base + cg * 16;
        const bool special = (c0 < wr0 + 64 && c0 + 16 > wr0) ||
                             (c0 < p0 + 64 && c0 + 16 > p0);
        if (!special) {
#pragma unroll
            for (int t = 0; t < 4; ++t) {
                float e0 = fast_exp2(acc[t][0]) + fast_exp2(acc[t][1]);
                float e1 = fast_exp2(acc[t][2]) + fast_exp2(acc[t][3]);
                sum_exp[t] += e0 + e1;
            }
        } else {
#pragma unroll
            for (int t = 0; t < 4; ++t) {
                const int r = wr0 + t * 16 + l15;
#pragma unroll
                for (int j = 0; j < 4; ++j) {
                    const int c = c0 + quad * 4 + j;
                    const float e = fast_exp2(acc[t][j]);
                    sum_exp[t] += (c == r) ? 0.f : e;               // self-diag mask
                    if (c == (r ^ N_HALF)) pos_acc += acc[t][j];    // positive (scaled)
                }
            }
        }
    }

    // Per-row partial: reduce over the 4 quads, one coalesced store per row.
#pragma unroll
    for (int t = 0; t < 4; ++t) {
        float s = sum_exp[t];
        s += __shfl_xor(s, 16, 64);
        s += __shfl_xor(s, 32, 64);
        if (lane < 16)
            rowsum_part[(size_t)strip * TWO_N + wr0 + t * 16 + lane] = s;
    }

    // Positive partial: every wave writes its slot (0 if no partner overlap).
#pragma unroll
    for (int m = 1; m < 64; m <<= 1) pos_acc += __shfl_xor(pos_acc, m, 64);
    if (lane == 0) pos_part[blockIdx.x * 4 + wave] = pos_acc;
}

// ---------------------------------------------------------------------------
// Kernel 3: per-row ln(sum of 64 strip partials) - ln2 * positive partials.
// ---------------------------------------------------------------------------
__global__ __launch_bounds__(1024) void fin1_kernel(const float* __restrict__ rowsum_part,
                                                    const float* __restrict__ pos_part,
                                                    float* __restrict__ block_part)
{
    __shared__ float red[16];
    const int t = threadIdx.x;
    const int r = blockIdx.x * 1024 + t;
    float acc = 0.f;
#pragma unroll
    for (int cs = 0; cs < 64; ++cs)
        acc += rowsum_part[(size_t)cs * TWO_N + r];
    float v = logf(acc) - 0.69314718055994531f * pos_part[blockIdx.x * 1024 + t];
#pragma unroll
    for (int m = 1; m < 64; m <<= 1) v += __shfl_xor(v, m, 64);
    if ((t & 63) == 0) red[t >> 6] = v;
    __syncthreads();
    if (t == 0) {
        float s = 0.f;
#pragma unroll
        for (int w = 0; w < 16; ++w) s += red[w];
        block_part[blockIdx.x] = s;
    }
}

__global__ void fin2_kernel(const float* __restrict__ block_part, float* __restrict__ out)
{
    if (threadIdx.x == 0) {
        float s = 0.f;
#pragma unroll
        for (int i = 0; i < 8; ++i) s += block_part[i];
        out[0] = s / (float)TWO_N;
    }
}

// ---------------------------------------------------------------------------
extern "C" void kernel_launch(void* const* d_in, const int* in_sizes, int n_in,
                              void* d_out, int out_size, void* d_ws, size_t ws_size,
                              hipStream_t stream)
{
    const float* zis = (const float*)d_in[0];
    const float* zjs = (const float*)d_in[1];

    // ws: [0,2MB) swizzled fp8; rowsum partials [64][8192] f32 (2MB);
    //     pos partials [8192]; block partials [8].
    unsigned char* swz = (unsigned char*)d_ws;
    float* rowsum_part = (float*)((char*)d_ws + (size_t)TWO_N * DIMS);
    float* pos_part    = rowsum_part + (size_t)64 * TWO_N;
    float* block_part  = pos_part + 8192;

    nrm_kernel<<<TWO_N / 8, 256, 0, stream>>>(zis, zjs, swz);
    ntx_kernel<<<2048, 256, 0, stream>>>(swz, rowsum_part, pos_part);
    fin1_kernel<<<8, 1024, 0, stream>>>(rowsum_part, pos_part, block_part);
    fin2_kernel<<<1, 64, 0, stream>>>(block_part, (float*)d_out);
}